// Round 1
// baseline (240.600 us; speedup 1.0000x reference)
//
#include <hip/hip_runtime.h>

// Sizes (compile-time constants for this problem)
constexpr int B = 16, T = 300, U = 30;
constexpr int J = 512;      // ENC_DIM = DEC_DIM = JOINER_DIM
constexpr int V = 500;      // VOCAB
constexpr int BT = B * T;   // 4800
constexpr int BU = B * U;   // 480

// ---------------------------------------------------------------------------
// Generic tiled fp32 GEMM: C(M x N) = A(M x K) @ B(N x K)^T + bias(N)
// 64x64 tile, BK=16, 256 threads, 4x4 outputs per thread.
// ---------------------------------------------------------------------------
#define BM 64
#define BN 64
#define BKK 16
#define LDP 68   // padded LDS leading dim (16B-aligned rows, staggered banks)

__global__ __launch_bounds__(256) void gemm_abt_bias(
    const float* __restrict__ A, const float* __restrict__ Bm,
    const float* __restrict__ bias, float* __restrict__ C,
    int M, int N, int K)
{
    __shared__ float As[BKK][LDP];
    __shared__ float Bs[BKK][LDP];

    const int tid = threadIdx.x;
    const int tx = tid & 15;          // 0..15 -> n sub-tile
    const int ty = tid >> 4;          // 0..15 -> m sub-tile
    const int m0 = blockIdx.y * BM;
    const int n0 = blockIdx.x * BN;

    const int lm = tid >> 2;          // 0..63  (row within tile)
    const int lk = (tid & 3) * 4;     // 0,4,8,12 (k offset, float4)

    float acc[4][4] = {};

    for (int k0 = 0; k0 < K; k0 += BKK) {
        // Stage A tile (rows m0..m0+63, cols k0..k0+15), stored transposed As[k][m]
        {
            float4 v = make_float4(0.f, 0.f, 0.f, 0.f);
            int m = m0 + lm;
            if (m < M) v = *reinterpret_cast<const float4*>(&A[(size_t)m * K + k0 + lk]);
            As[lk + 0][lm] = v.x; As[lk + 1][lm] = v.y;
            As[lk + 2][lm] = v.z; As[lk + 3][lm] = v.w;
        }
        // Stage B tile (rows n0..n0+63 of Bm, cols k0..k0+15), Bs[k][n]
        {
            float4 v = make_float4(0.f, 0.f, 0.f, 0.f);
            int n = n0 + lm;
            if (n < N) v = *reinterpret_cast<const float4*>(&Bm[(size_t)n * K + k0 + lk]);
            Bs[lk + 0][lm] = v.x; Bs[lk + 1][lm] = v.y;
            Bs[lk + 2][lm] = v.z; Bs[lk + 3][lm] = v.w;
        }
        __syncthreads();

        #pragma unroll
        for (int k = 0; k < BKK; ++k) {
            float a[4], b[4];
            #pragma unroll
            for (int i = 0; i < 4; ++i) a[i] = As[k][ty * 4 + i];
            #pragma unroll
            for (int j = 0; j < 4; ++j) b[j] = Bs[k][tx * 4 + j];
            #pragma unroll
            for (int i = 0; i < 4; ++i)
                #pragma unroll
                for (int j = 0; j < 4; ++j)
                    acc[i][j] += a[i] * b[j];
        }
        __syncthreads();
    }

    #pragma unroll
    for (int i = 0; i < 4; ++i) {
        int m = m0 + ty * 4 + i;
        if (m >= M) continue;
        #pragma unroll
        for (int j = 0; j < 4; ++j) {
            int n = n0 + tx * 4 + j;
            if (n < N) {
                float vv = acc[i][j] + (bias ? bias[n] : 0.0f);
                C[(size_t)m * N + n] = vv;
            }
        }
    }
}

// ---------------------------------------------------------------------------
// Broadcast add: out[b,t,u,v] = EV[b*T+t, v] + DV[b*U+u, v]
// One block per (b,t); EV row cached in LDS; float4 streams.
// V = 500 -> 125 float4 per row.
// ---------------------------------------------------------------------------
constexpr int V4 = V / 4;  // 125

__global__ __launch_bounds__(256) void bcast_add(
    const float* __restrict__ EV, const float* __restrict__ DV,
    float* __restrict__ out)
{
    __shared__ float4 evs[V4];
    const int bt = blockIdx.x;          // 0..BT-1
    const int b  = bt / T;

    const float4* evrow = reinterpret_cast<const float4*>(EV + (size_t)bt * V);
    for (int i = threadIdx.x; i < V4; i += 256) evs[i] = evrow[i];
    __syncthreads();

    const float4* dvb  = reinterpret_cast<const float4*>(DV + (size_t)b * U * V);
    float4*       orow = reinterpret_cast<float4*>(out + (size_t)bt * U * V);

    for (int i = threadIdx.x; i < U * V4; i += 256) {
        int v = i % V4;
        float4 e = evs[v];
        float4 d = dvb[i];
        float4 r;
        r.x = e.x + d.x; r.y = e.y + d.y; r.z = e.z + d.z; r.w = e.w + d.w;
        orow[i] = r;
    }
}

extern "C" void kernel_launch(void* const* d_in, const int* in_sizes, int n_in,
                              void* d_out, int out_size, void* d_ws, size_t ws_size,
                              hipStream_t stream) {
    const float* enc   = (const float*)d_in[0];  // (B,T,512)
    const float* dec   = (const float*)d_in[1];  // (B,U,512)
    const float* W_enc = (const float*)d_in[2];  // (512,512)
    const float* b_enc = (const float*)d_in[3];  // (512,)
    const float* W_dec = (const float*)d_in[4];  // (512,512)
    const float* b_dec = (const float*)d_in[5];  // (512,)
    const float* W_out = (const float*)d_in[6];  // (500,512)
    const float* b_out = (const float*)d_in[7];  // (500,)
    float* out = (float*)d_out;

    // Workspace layout (floats): encProj | decProj | EV | DV  (~21.4 MB total)
    float* ws      = (float*)d_ws;
    float* encProj = ws;                              // BT*J
    float* decProj = encProj + (size_t)BT * J;        // BU*J
    float* EV      = decProj + (size_t)BU * J;        // BT*V
    float* DV      = EV      + (size_t)BT * V;        // BU*V

    dim3 blk(256);

    // encProj = enc @ W_enc^T + b_enc   (4800 x 512, K=512)
    gemm_abt_bias<<<dim3(J / BN, BT / BM), blk, 0, stream>>>(
        enc, W_enc, b_enc, encProj, BT, J, J);
    // decProj = dec @ W_dec^T + b_dec   (480 x 512, K=512)
    gemm_abt_bias<<<dim3(J / BN, (BU + BM - 1) / BM), blk, 0, stream>>>(
        dec, W_dec, b_dec, decProj, BU, J, J);
    // EV = encProj @ W_out^T            (4800 x 500, K=512)
    gemm_abt_bias<<<dim3((V + BN - 1) / BN, BT / BM), blk, 0, stream>>>(
        encProj, W_out, nullptr, EV, BT, V, J);
    // DV = decProj @ W_out^T + b_out    (480 x 500, K=512)
    gemm_abt_bias<<<dim3((V + BN - 1) / BN, (BU + BM - 1) / BM), blk, 0, stream>>>(
        decProj, W_out, b_out, DV, BU, V, J);

    // out[b,t,u,v] = EV[bt,v] + DV[bu,v]
    bcast_add<<<dim3(BT), blk, 0, stream>>>(EV, DV, out);
}

// Round 2
// 131.379 us; speedup vs baseline: 1.8313x; 1.8313x over previous
//
#include <hip/hip_runtime.h>

// Problem sizes (compile-time)
constexpr int B_ = 16, T_ = 300, U_ = 30;
constexpr int J_ = 512;       // ENC_DIM = DEC_DIM = JOINER_DIM
constexpr int V_ = 500;       // VOCAB
constexpr int BT_ = B_ * T_;  // 4800
constexpr int BU_ = B_ * U_;  // 480
constexpr int KD = 512;       // K for all GEMMs
constexpr int NPAD = 512;     // padded N / row stride for workspace matrices

typedef __attribute__((ext_vector_type(8))) short short8v;  // 8 bf16 (4 VGPRs)
typedef __attribute__((ext_vector_type(4))) float f32x4;    // MFMA accumulator

__device__ __forceinline__ ushort f2bf(float f) {
    // fp32 -> bf16, round-to-nearest-even
    unsigned u = __builtin_bit_cast(unsigned, f);
    u += 0x7FFFu + ((u >> 16) & 1u);
    return (ushort)(u >> 16);
}

// ---------------------------------------------------------------------------
// MFMA GEMM: C(M x Npad) = A(M x 512) @ B(Nreal x 512)^T [+ bias]
//   A: fp32 or bf16 (row-major, stride 512). B: fp32 (row-major, stride 512).
//   C: fp32 or bf16, row stride NPAD=512. Rows of B >= Nreal are zero-filled.
// 64x64 block tile, BK=32, 4 waves (2x2), each wave 32x32 via 2x2 16x16x32 MFMA.
// LDS [64][32] bf16: staging writes contiguous; frag read = 1x ds_read_b128
// at the b128 bank floor (8 slots/bank, conflict-free per m136 semantics).
// ---------------------------------------------------------------------------
template <bool A_BF16, bool OUT_BF16>
__global__ __launch_bounds__(256) void mfma_gemm(
    const void* __restrict__ Ap, const float* __restrict__ Bp,
    const float* __restrict__ bias, void* __restrict__ Cp,
    int M, int Nreal)
{
    __shared__ ushort a_s[64 * 32];
    __shared__ ushort b_s[64 * 32];

    const int tid  = threadIdx.x;
    const int lane = tid & 63;
    const int wave = tid >> 6;
    const int wm   = wave >> 1;       // 0..1  wave row
    const int wn   = wave & 1;        // 0..1  wave col
    const int m0   = blockIdx.y * 64;
    const int n0   = blockIdx.x * 64;

    const int srow = tid >> 2;        // 0..63  staging row
    const int skc  = tid & 3;         // 0..3   staging k-chunk (8 elems)

    const int r16 = lane & 15;
    const int kc  = lane >> 4;        // frag k-chunk

    f32x4 acc[2][2] = {};

    for (int k0 = 0; k0 < KD; k0 += 32) {
        // ---- stage A tile (64 rows x 32 k) as bf16 ----
        {
            const int gm = m0 + srow;
            short8v av = {};
            if (gm < M) {
                if constexpr (A_BF16) {
                    av = *reinterpret_cast<const short8v*>(
                        (const ushort*)Ap + (size_t)gm * KD + k0 + skc * 8);
                } else {
                    const float* ap = (const float*)Ap + (size_t)gm * KD + k0 + skc * 8;
                    float4 f0 = *reinterpret_cast<const float4*>(ap);
                    float4 f1 = *reinterpret_cast<const float4*>(ap + 4);
                    av[0] = (short)f2bf(f0.x); av[1] = (short)f2bf(f0.y);
                    av[2] = (short)f2bf(f0.z); av[3] = (short)f2bf(f0.w);
                    av[4] = (short)f2bf(f1.x); av[5] = (short)f2bf(f1.y);
                    av[6] = (short)f2bf(f1.z); av[7] = (short)f2bf(f1.w);
                }
            }
            *reinterpret_cast<short8v*>(&a_s[srow * 32 + skc * 8]) = av;
        }
        // ---- stage B tile (64 cols x 32 k), fp32 source, zero past Nreal ----
        {
            const int gn = n0 + srow;
            short8v bv = {};
            if (gn < Nreal) {
                const float* bp = Bp + (size_t)gn * KD + k0 + skc * 8;
                float4 f0 = *reinterpret_cast<const float4*>(bp);
                float4 f1 = *reinterpret_cast<const float4*>(bp + 4);
                bv[0] = (short)f2bf(f0.x); bv[1] = (short)f2bf(f0.y);
                bv[2] = (short)f2bf(f0.z); bv[3] = (short)f2bf(f0.w);
                bv[4] = (short)f2bf(f1.x); bv[5] = (short)f2bf(f1.y);
                bv[6] = (short)f2bf(f1.z); bv[7] = (short)f2bf(f1.w);
            }
            *reinterpret_cast<short8v*>(&b_s[srow * 32 + skc * 8]) = bv;
        }
        __syncthreads();

        // ---- fragments + MFMA ----
        const short8v af0 = *reinterpret_cast<const short8v*>(
            &a_s[(wm * 32 + 0 + r16) * 32 + kc * 8]);
        const short8v af1 = *reinterpret_cast<const short8v*>(
            &a_s[(wm * 32 + 16 + r16) * 32 + kc * 8]);
        const short8v bf0 = *reinterpret_cast<const short8v*>(
            &b_s[(wn * 32 + 0 + r16) * 32 + kc * 8]);
        const short8v bf1 = *reinterpret_cast<const short8v*>(
            &b_s[(wn * 32 + 16 + r16) * 32 + kc * 8]);

        acc[0][0] = __builtin_amdgcn_mfma_f32_16x16x32_bf16(af0, bf0, acc[0][0], 0, 0, 0);
        acc[0][1] = __builtin_amdgcn_mfma_f32_16x16x32_bf16(af0, bf1, acc[0][1], 0, 0, 0);
        acc[1][0] = __builtin_amdgcn_mfma_f32_16x16x32_bf16(af1, bf0, acc[1][0], 0, 0, 0);
        acc[1][1] = __builtin_amdgcn_mfma_f32_16x16x32_bf16(af1, bf1, acc[1][1], 0, 0, 0);
        __syncthreads();
    }

    // ---- epilogue: C/D layout col=lane&15, row=(lane>>4)*4+reg (m89-verified) ----
    const int rb = (lane >> 4) * 4;
    #pragma unroll
    for (int m = 0; m < 2; ++m) {
        const int grow_base = m0 + wm * 32 + m * 16 + rb;
        #pragma unroll
        for (int n = 0; n < 2; ++n) {
            const int gcol = n0 + wn * 32 + n * 16 + r16;
            float bv = 0.0f;
            if (bias != nullptr && gcol < Nreal) bv = bias[gcol];
            #pragma unroll
            for (int r = 0; r < 4; ++r) {
                const int grow = grow_base + r;
                if (grow < M) {
                    const float v = acc[m][n][r] + bv;
                    if constexpr (OUT_BF16)
                        ((ushort*)Cp)[(size_t)grow * NPAD + gcol] = f2bf(v);
                    else
                        ((float*)Cp)[(size_t)grow * NPAD + gcol] = v;
                }
            }
        }
    }
}

// ---------------------------------------------------------------------------
// Broadcast add: out[b,t,u,v] = EV[bt, v] + DV[b*U+u, v]   (v < 500)
// EV/DV row stride NPAD=512; out dense 500. One block per (b,t).
// ---------------------------------------------------------------------------
constexpr int V4 = V_ / 4;  // 125

__global__ __launch_bounds__(256) void bcast_add(
    const float* __restrict__ EV, const float* __restrict__ DV,
    float* __restrict__ out)
{
    __shared__ float evs[V_];
    const int bt = blockIdx.x;
    const int b  = bt / T_;

    const float4* evrow = reinterpret_cast<const float4*>(EV + (size_t)bt * NPAD);
    if (threadIdx.x < V4)
        reinterpret_cast<float4*>(evs)[threadIdx.x] = evrow[threadIdx.x];
    __syncthreads();

    const float* dvb  = DV + (size_t)b * U_ * NPAD;
    float4*      orow = reinterpret_cast<float4*>(out + (size_t)bt * U_ * V_);

    for (int i = threadIdx.x; i < U_ * V4; i += 256) {
        const int u = i / V4;
        const int v = i - u * V4;
        const float4 d = *reinterpret_cast<const float4*>(dvb + u * NPAD + v * 4);
        const float4 e = reinterpret_cast<const float4*>(evs)[v];
        float4 r;
        r.x = e.x + d.x; r.y = e.y + d.y; r.z = e.z + d.z; r.w = e.w + d.w;
        orow[i] = r;
    }
}

extern "C" void kernel_launch(void* const* d_in, const int* in_sizes, int n_in,
                              void* d_out, int out_size, void* d_ws, size_t ws_size,
                              hipStream_t stream) {
    const float* enc   = (const float*)d_in[0];  // (B,T,512)
    const float* dec   = (const float*)d_in[1];  // (B,U,512)
    const float* W_enc = (const float*)d_in[2];  // (512,512)
    const float* b_enc = (const float*)d_in[3];  // (512,)
    const float* W_dec = (const float*)d_in[4];  // (512,512)
    const float* b_dec = (const float*)d_in[5];  // (512,)
    const float* W_out = (const float*)d_in[6];  // (500,512)
    const float* b_out = (const float*)d_in[7];  // (500,)
    float* out = (float*)d_out;

    // Workspace: encProj(bf16) | decProj(bf16) | EV(f32) | DV(f32)  (~16.2 MB)
    ushort* encProj = (ushort*)d_ws;
    ushort* decProj = encProj + (size_t)BT_ * NPAD;
    float*  EV      = (float*)(decProj + (size_t)BU_ * NPAD);
    float*  DV      = EV + (size_t)BT_ * NPAD;

    dim3 blk(256);

    // encProj = bf16(enc @ W_enc^T + b_enc)          (4800 x 512)
    mfma_gemm<false, true><<<dim3(NPAD / 64, BT_ / 64), blk, 0, stream>>>(
        enc, W_enc, b_enc, encProj, BT_, 512);
    // decProj = bf16(dec @ W_dec^T + b_dec)          (480 x 512)
    mfma_gemm<false, true><<<dim3(NPAD / 64, (BU_ + 63) / 64), blk, 0, stream>>>(
        dec, W_dec, b_dec, decProj, BU_, 512);
    // EV = encProj @ W_out^T                         (4800 x 500, padded 512)
    mfma_gemm<true, false><<<dim3(NPAD / 64, BT_ / 64), blk, 0, stream>>>(
        encProj, W_out, nullptr, EV, BT_, V_);
    // DV = decProj @ W_out^T + b_out                 (480 x 500, padded 512)
    mfma_gemm<true, false><<<dim3(NPAD / 64, (BU_ + 63) / 64), blk, 0, stream>>>(
        decProj, W_out, b_out, DV, BU_, V_);

    // out[b,t,u,v] = EV[bt,v] + DV[bu,v]
    bcast_add<<<dim3(BT_), blk, 0, stream>>>(EV, DV, out);
}

// Round 3
// 83.642 us; speedup vs baseline: 2.8766x; 1.5707x over previous
//
#include <hip/hip_runtime.h>

// Problem sizes (compile-time)
constexpr int B_ = 16, T_ = 300, U_ = 30;
constexpr int J_ = 512;       // ENC/DEC/JOINER dim
constexpr int V_ = 500;       // VOCAB
constexpr int BT_ = B_ * T_;  // 4800 (divisible by 64)
constexpr int BU_ = B_ * U_;  // 480
constexpr int KD  = 512;      // K of all GEMMs
constexpr int NP  = 512;      // padded N / row stride

typedef __attribute__((ext_vector_type(8))) short short8v;  // 8 bf16
typedef __attribute__((ext_vector_type(4))) float f32x4;

__device__ __forceinline__ ushort f2bf(float f) {
    unsigned u = __builtin_bit_cast(unsigned, f);
    u += 0x7FFFu + ((u >> 16) & 1u);
    return (ushort)(u >> 16);
}

// direct global->LDS async copy, 16B per lane (wave-uniform LDS base)
#define GLOAD16(gsrc, ldst)                                                   \
    __builtin_amdgcn_global_load_lds(                                         \
        (const __attribute__((address_space(1))) unsigned int*)(const void*)(gsrc), \
        (__attribute__((address_space(3))) unsigned int*)(void*)(ldst), 16, 0, 0)

// ---------------------------------------------------------------------------
// prep: one launch, role by blockIdx.x range
//  [0,1200)    enc f32 -> encB bf16            (4800x512)
//  [1200,1328) dec f32 -> decB bf16, rows 480..511 zeroed (512x512)
//  [1328,1392) W_enc^T -> WeT bf16             (WeT[d][j] = W_enc[j][d])
//  [1392,1456) W_dec^T -> WdT bf16
//  [1456,1584) W_out -> WoB bf16 (rows 500..511 zero) + be/bd bias dots
// ---------------------------------------------------------------------------
__global__ __launch_bounds__(256) void prep(
    const float* __restrict__ enc, const float* __restrict__ dec,
    const float* __restrict__ W_enc, const float* __restrict__ W_dec,
    const float* __restrict__ W_out, const float* __restrict__ b_enc,
    const float* __restrict__ b_dec, const float* __restrict__ b_out,
    ushort* __restrict__ encB, ushort* __restrict__ decB,
    ushort* __restrict__ WeT, ushort* __restrict__ WdT,
    ushort* __restrict__ WoB, float* __restrict__ be, float* __restrict__ bd)
{
    __shared__ ushort ts[64][65];
    const int bid = blockIdx.x;
    const int tid = threadIdx.x;

    if (bid < 1200) {                       // enc convert: 2048 floats/block
        const size_t idx = (size_t)bid * 2048 + tid * 8;
        float4 f0 = *reinterpret_cast<const float4*>(enc + idx);
        float4 f1 = *reinterpret_cast<const float4*>(enc + idx + 4);
        short8v o; o[0]=(short)f2bf(f0.x); o[1]=(short)f2bf(f0.y);
        o[2]=(short)f2bf(f0.z); o[3]=(short)f2bf(f0.w);
        o[4]=(short)f2bf(f1.x); o[5]=(short)f2bf(f1.y);
        o[6]=(short)f2bf(f1.z); o[7]=(short)f2bf(f1.w);
        *reinterpret_cast<short8v*>(encB + idx) = o;
    } else if (bid < 1328) {                // dec convert + pad
        const size_t idx = (size_t)(bid - 1200) * 2048 + tid * 8;
        const int row = (int)(idx >> 9);
        short8v o = {};
        if (row < BU_) {
            float4 f0 = *reinterpret_cast<const float4*>(dec + idx);
            float4 f1 = *reinterpret_cast<const float4*>(dec + idx + 4);
            o[0]=(short)f2bf(f0.x); o[1]=(short)f2bf(f0.y);
            o[2]=(short)f2bf(f0.z); o[3]=(short)f2bf(f0.w);
            o[4]=(short)f2bf(f1.x); o[5]=(short)f2bf(f1.y);
            o[6]=(short)f2bf(f1.z); o[7]=(short)f2bf(f1.w);
        }
        *reinterpret_cast<short8v*>(decB + idx) = o;
    } else if (bid < 1456) {                // transpose W_enc / W_dec (64x64 tiles)
        const bool isE = bid < 1392;
        const int t = bid - (isE ? 1328 : 1392);   // 0..63
        const float*  W = isE ? W_enc : W_dec;
        ushort*      WT = isE ? WeT : WdT;
        const int r0 = (t >> 3) * 64, c0 = (t & 7) * 64;
        #pragma unroll
        for (int it = 0; it < 4; ++it) {
            const int idx = tid + it * 256;        // 0..1023
            const int r = idx >> 4, c4 = (idx & 15) * 4;
            float4 f = *reinterpret_cast<const float4*>(&W[(size_t)(r0 + r) * 512 + c0 + c4]);
            ts[r][c4 + 0] = f2bf(f.x); ts[r][c4 + 1] = f2bf(f.y);
            ts[r][c4 + 2] = f2bf(f.z); ts[r][c4 + 3] = f2bf(f.w);
        }
        __syncthreads();
        #pragma unroll
        for (int it = 0; it < 4; ++it) {
            const int idx = tid + it * 256;
            const int c = idx >> 4, r4 = (idx & 15) * 4;
            ushort4 o;
            o.x = ts[r4 + 0][c]; o.y = ts[r4 + 1][c];
            o.z = ts[r4 + 2][c]; o.w = ts[r4 + 3][c];
            *reinterpret_cast<ushort4*>(&WT[(size_t)(c0 + c) * 512 + r0 + r4]) = o;
        }
    } else {                                // W_out rows + folded biases
        const int v    = (bid - 1456) * 4 + (tid >> 6);  // 0..511
        const int lane = tid & 63;
        float4 f0 = make_float4(0, 0, 0, 0), f1 = f0;
        if (v < V_) {
            f0 = *reinterpret_cast<const float4*>(&W_out[(size_t)v * 512 + lane * 8]);
            f1 = *reinterpret_cast<const float4*>(&W_out[(size_t)v * 512 + lane * 8 + 4]);
        }
        short8v o; o[0]=(short)f2bf(f0.x); o[1]=(short)f2bf(f0.y);
        o[2]=(short)f2bf(f0.z); o[3]=(short)f2bf(f0.w);
        o[4]=(short)f2bf(f1.x); o[5]=(short)f2bf(f1.y);
        o[6]=(short)f2bf(f1.z); o[7]=(short)f2bf(f1.w);
        *reinterpret_cast<short8v*>(WoB + (size_t)v * 512 + lane * 8) = o;

        float4 e0 = *reinterpret_cast<const float4*>(b_enc + lane * 8);
        float4 e1 = *reinterpret_cast<const float4*>(b_enc + lane * 8 + 4);
        float4 d0 = *reinterpret_cast<const float4*>(b_dec + lane * 8);
        float4 d1 = *reinterpret_cast<const float4*>(b_dec + lane * 8 + 4);
        float sE = f0.x*e0.x + f0.y*e0.y + f0.z*e0.z + f0.w*e0.w
                 + f1.x*e1.x + f1.y*e1.y + f1.z*e1.z + f1.w*e1.w;
        float sD = f0.x*d0.x + f0.y*d0.y + f0.z*d0.z + f0.w*d0.w
                 + f1.x*d1.x + f1.y*d1.y + f1.z*d1.z + f1.w*d1.w;
        #pragma unroll
        for (int off = 32; off > 0; off >>= 1) {
            sE += __shfl_down(sE, off);
            sD += __shfl_down(sD, off);
        }
        if (lane == 0) {
            be[v] = (v < V_) ? sE : 0.0f;
            bd[v] = (v < V_) ? (sD + b_out[v]) : 0.0f;
        }
    }
}

// ---------------------------------------------------------------------------
// bf16 NT GEMM, 64x64 tile, BK=32, global_load_lds staging.
// C(M x 512) = A(M x 512) @ B(512 x 512)^T [+ bias]; M multiple of 64.
// 4 waves (2x2), each wave 32x32 via 2x2 mfma_f32_16x16x32_bf16.
// ---------------------------------------------------------------------------
template <bool OUT_BF16>
__device__ __forceinline__ void gemm_body(
    const ushort* __restrict__ A, const ushort* __restrict__ Bm,
    const float* __restrict__ bias, void* __restrict__ C,
    int m0, int n0)
{
    __shared__ ushort a_s[64 * 32];
    __shared__ ushort b_s[64 * 32];

    const int tid  = threadIdx.x;
    const int lane = tid & 63;
    const int wave = tid >> 6;
    const int wm   = wave >> 1, wn = wave & 1;

    // staging: wave w covers LDS bytes [1024w, 1024w+1024); lane -> +16*lane
    // matching rows 16w + lane/4, k-chunk (lane&3)*8
    const int srow = (wave << 4) + (lane >> 2);
    const int skc  = (lane & 3) * 8;
    ushort* a_dst = a_s + wave * 512;   // ushort units: 1024B/wave
    ushort* b_dst = b_s + wave * 512;

    const int r16 = lane & 15;
    const int kc  = lane >> 4;

    f32x4 acc[2][2] = {};

    for (int k0 = 0; k0 < KD; k0 += 32) {
        GLOAD16(A  + (size_t)(m0 + srow) * KD + k0 + skc, a_dst);
        GLOAD16(Bm + (size_t)(n0 + srow) * KD + k0 + skc, b_dst);
        __syncthreads();   // drains vmcnt -> tiles resident

        const short8v af0 = *reinterpret_cast<const short8v*>(&a_s[(wm*32 +      r16) * 32 + kc*8]);
        const short8v af1 = *reinterpret_cast<const short8v*>(&a_s[(wm*32 + 16 + r16) * 32 + kc*8]);
        const short8v bf0 = *reinterpret_cast<const short8v*>(&b_s[(wn*32 +      r16) * 32 + kc*8]);
        const short8v bf1 = *reinterpret_cast<const short8v*>(&b_s[(wn*32 + 16 + r16) * 32 + kc*8]);

        acc[0][0] = __builtin_amdgcn_mfma_f32_16x16x32_bf16(af0, bf0, acc[0][0], 0, 0, 0);
        acc[0][1] = __builtin_amdgcn_mfma_f32_16x16x32_bf16(af0, bf1, acc[0][1], 0, 0, 0);
        acc[1][0] = __builtin_amdgcn_mfma_f32_16x16x32_bf16(af1, bf0, acc[1][0], 0, 0, 0);
        acc[1][1] = __builtin_amdgcn_mfma_f32_16x16x32_bf16(af1, bf1, acc[1][1], 0, 0, 0);
        __syncthreads();
    }

    const int rb = (lane >> 4) * 4;
    #pragma unroll
    for (int m = 0; m < 2; ++m) {
        const int grow0 = m0 + wm * 32 + m * 16 + rb;
        #pragma unroll
        for (int n = 0; n < 2; ++n) {
            const int gcol = n0 + wn * 32 + n * 16 + r16;
            const float bv = bias ? bias[gcol] : 0.0f;
            #pragma unroll
            for (int r = 0; r < 4; ++r) {
                const float v = acc[m][n][r] + bv;
                if constexpr (OUT_BF16)
                    ((ushort*)C)[(size_t)(grow0 + r) * NP + gcol] = f2bf(v);
                else
                    ((float*)C)[(size_t)(grow0 + r) * NP + gcol] = v;
            }
        }
    }
}

// Wc_enc = WoB @ WeT^T (z=0), Wc_dec = WoB @ WdT^T (z=1); 512x512 bf16 out
__global__ __launch_bounds__(256) void wc_gemm(
    const ushort* __restrict__ WoB, const ushort* __restrict__ WeT,
    const ushort* __restrict__ WdT, ushort* __restrict__ WcE,
    ushort* __restrict__ WcD)
{
    const bool z = blockIdx.z != 0;
    gemm_body<true>(WoB, z ? WdT : WeT, nullptr, z ? WcD : WcE,
                    blockIdx.y * 64, blockIdx.x * 64);
}

// z=0: EV = encB @ WcE^T + be (4800x512) ; z=1: DV = decB @ WcD^T + bd (512x512)
__global__ __launch_bounds__(256) void evdv_gemm(
    const ushort* __restrict__ encB, const ushort* __restrict__ WcE,
    const float* __restrict__ be, float* __restrict__ EV,
    const ushort* __restrict__ decB, const ushort* __restrict__ WcD,
    const float* __restrict__ bd, float* __restrict__ DV)
{
    const bool z = blockIdx.z != 0;
    if (z && blockIdx.y >= 8) return;     // DV has only 512 rows
    gemm_body<false>(z ? decB : encB, z ? WcD : WcE, z ? bd : be,
                     z ? DV : EV, blockIdx.y * 64, blockIdx.x * 64);
}

// ---------------------------------------------------------------------------
// out[b,t,u,v] = EV[bt,v] + DV[b*U+u,v], v<500; EV/DV stride 512
// ---------------------------------------------------------------------------
constexpr int V4 = V_ / 4;  // 125

__global__ __launch_bounds__(256) void bcast_add(
    const float* __restrict__ EV, const float* __restrict__ DV,
    float* __restrict__ out)
{
    __shared__ float evs[V_];
    const int bt = blockIdx.x;
    const int b  = bt / T_;

    const float4* evrow = reinterpret_cast<const float4*>(EV + (size_t)bt * NP);
    if (threadIdx.x < V4)
        reinterpret_cast<float4*>(evs)[threadIdx.x] = evrow[threadIdx.x];
    __syncthreads();

    const float* dvb  = DV + (size_t)b * U_ * NP;
    float4*      orow = reinterpret_cast<float4*>(out + (size_t)bt * U_ * V_);

    for (int i = threadIdx.x; i < U_ * V4; i += 256) {
        const int u = i / V4;
        const int v = i - u * V4;
        const float4 d = *reinterpret_cast<const float4*>(dvb + u * NP + v * 4);
        const float4 e = reinterpret_cast<const float4*>(evs)[v];
        float4 r;
        r.x = e.x + d.x; r.y = e.y + d.y; r.z = e.z + d.z; r.w = e.w + d.w;
        orow[i] = r;
    }
}

extern "C" void kernel_launch(void* const* d_in, const int* in_sizes, int n_in,
                              void* d_out, int out_size, void* d_ws, size_t ws_size,
                              hipStream_t stream) {
    const float* enc   = (const float*)d_in[0];
    const float* dec   = (const float*)d_in[1];
    const float* W_enc = (const float*)d_in[2];
    const float* b_enc = (const float*)d_in[3];
    const float* W_dec = (const float*)d_in[4];
    const float* b_dec = (const float*)d_in[5];
    const float* W_out = (const float*)d_in[6];
    const float* b_out = (const float*)d_in[7];
    float* out = (float*)d_out;

    // Workspace layout (16B aligned): ~19 MB
    char* p = (char*)d_ws;
    ushort* encB = (ushort*)p;            p += (size_t)BT_ * 512 * 2;   // 4.92 MB
    ushort* decB = (ushort*)p;            p += (size_t)512 * 512 * 2;
    ushort* WeT  = (ushort*)p;            p += (size_t)512 * 512 * 2;
    ushort* WdT  = (ushort*)p;            p += (size_t)512 * 512 * 2;
    ushort* WoB  = (ushort*)p;            p += (size_t)512 * 512 * 2;
    ushort* WcE  = (ushort*)p;            p += (size_t)512 * 512 * 2;
    ushort* WcD  = (ushort*)p;            p += (size_t)512 * 512 * 2;
    float*  be   = (float*)p;             p += 512 * 4;
    float*  bd   = (float*)p;             p += 512 * 4;
    float*  EV   = (float*)p;             p += (size_t)BT_ * 512 * 4;   // 9.83 MB
    float*  DV   = (float*)p;

    dim3 blk(256);

    prep<<<dim3(1584), blk, 0, stream>>>(
        enc, dec, W_enc, W_dec, W_out, b_enc, b_dec, b_out,
        encB, decB, WeT, WdT, WoB, be, bd);

    wc_gemm<<<dim3(8, 8, 2), blk, 0, stream>>>(WoB, WeT, WdT, WcE, WcD);

    evdv_gemm<<<dim3(8, BT_ / 64, 2), blk, 0, stream>>>(
        encB, WcE, be, EV, decB, WcD, bd, DV);

    bcast_add<<<dim3(BT_), blk, 0, stream>>>(EV, DV, out);
}